// Round 6
// baseline (55.595 us; speedup 1.0000x reference)
//
#include <hip/hip_runtime.h>

// B=1024, A=256, E=4, M1=128, M2=16, H1=32, H2=64
#define XROW 1537
#define NTHR 512
#define SP   320              // padded slot space: 5 tiles x 64 (max St4 = 268)

// ws layout (floats): [0,128) Tsort[4][32]; [128,128+16896) AC[e][33][64][2]
// h2_pre[o] = v*A_k[o] + C_k[o] on interval k — exact piecewise-affine
// collapse of relu(v*W1+b1) @ W2 + b2 in the scalar v.

__global__ void __launch_bounds__(256)
be_prep(const float* __restrict__ W1, const float* __restrict__ b1,
        const float* __restrict__ W2, const float* __restrict__ b2,
        float* __restrict__ ws)
{
    __shared__ float t_s[4][32], w1_s[4][32], b1_s[4][32];
    __shared__ int   sidx[4][32];
    const int w = threadIdx.x >> 6, lane = threadIdx.x & 63;
    const int e = w;                       // one expert per wave

    if (lane < 32) {
        float w1v = W1[e * 32 + lane];
        float b1v = b1[e * 32 + lane];
        w1_s[e][lane] = w1v;
        b1_s[e][lane] = b1v;
        t_s[e][lane] = (w1v != 0.f) ? (-b1v / w1v) : 3.4e38f;
    }
    __syncthreads();
    if (lane < 32) {
        float ti = t_s[e][lane];
        int rank = 0;
        for (int j = 0; j < 32; ++j) {
            float tj = t_s[e][j];
            rank += (tj < ti) || (tj == ti && j < lane);
        }
        sidx[e][rank] = lane;
        ws[e * 32 + rank] = ti;            // sorted thresholds
    }
    __syncthreads();

    float* AC = ws + 128;
    const int o = lane;
    float A = 0.f, C = b2[e * 64 + o];
    for (int i = 0; i < 32; ++i) {         // active set at v = -inf
        float w1v = w1_s[e][i], b1v = b1_s[e][i];
        if ((w1v < 0.f) || (w1v == 0.f && b1v > 0.f)) {
            float w2v = W2[(e * 32 + i) * 64 + o];
            A = fmaf(w1v, w2v, A);
            C = fmaf(b1v, w2v, C);
        }
    }
    AC[(e * 33 + 0) * 128 + 2 * o]     = A;
    AC[(e * 33 + 0) * 128 + 2 * o + 1] = C;
    for (int k = 1; k <= 32; ++k) {
        int i = sidx[e][k - 1];
        float w1v = w1_s[e][i], b1v = b1_s[e][i];
        float w2v = W2[(e * 32 + i) * 64 + o];
        if (w1v > 0.f)      { A += w1v * w2v; C += b1v * w2v; }  // turns on
        else if (w1v < 0.f) { A -= w1v * w2v; C -= b1v * w2v; }  // turns off
        AC[(e * 33 + k) * 128 + 2 * o]     = A;
        AC[(e * 33 + k) * 128 + 2 * o + 1] = C;
    }
}

__global__ void __launch_bounds__(NTHR)
be_kernel(const float* __restrict__ x,
          const float* __restrict__ W3, const float* __restrict__ b3,
          const float* __restrict__ wsr,
          float* __restrict__ out)
{
    __shared__ float vca[SP];                       // compacted v (pads = 0)
    __shared__ __align__(16) float RmT[4][SP];      // [c][slot], mask folded
    __shared__ __align__(16) float H2T[64][68];     // [i][a_local]
    __shared__ __align__(16) float S2[2][4][4][64]; // [half][e][c][i]
    __shared__ float Tpart[4][4][32];
    __shared__ float T16[16];
    __shared__ float Pp[2][128 * 5];                // P partials (expert-pairs)
    __shared__ float Ts_l[128];                     // sorted thresholds
    __shared__ int   kea[SP];                       // per-slot AC base offset
    __shared__ int   cntw[8][4];

    const int tid  = threadIdx.x;
    const int b    = blockIdx.x;
    const int lane = tid & 63;
    const int w    = tid >> 6;
    const long xb  = (long)b * XROW;
    const float* ACg = wsr + 128;

    // ---- per-a input (a = tid < 256) ----
    float v = 0.f;
    int e = -1;                                     // waves 4..7: no match
    int N = 0;
    float maskf = 0.f;
    if (tid < 256) {
        v = x[xb + 2 * tid];
        e = (int)x[xb + 2 * tid + 1];
        e = max(0, min(3, e));
        N = (int)x[xb + 1536];
        maskf = (tid < N) ? 1.f : 0.f;
    }
    if (tid < 128) Ts_l[tid] = wsr[tid];

    // ---- ballot compaction (waves 4..7 contribute zero counts) ----
    unsigned long long mybal = 0ull;
    #pragma unroll
    for (int q = 0; q < 4; ++q) {
        unsigned long long bq = __ballot(e == q);
        if (lane == 0) cntw[w][q] = __popcll(bq);
        if (e == q) mybal = bq;
    }
    int rank = __popcll(mybal & ((1ull << lane) - 1ull));

    // zero padded arrays before scatter
    if (tid < SP) { vca[tid] = 0.f; kea[tid] = 0; }
    for (int idx = tid; idx < 4 * SP; idx += NTHR) (&RmT[0][0])[idx] = 0.f;
    __syncthreads();

    int c0 = cntw[0][0] + cntw[1][0] + cntw[2][0] + cntw[3][0];
    int c1 = cntw[0][1] + cntw[1][1] + cntw[2][1] + cntw[3][1];
    int c2_ = cntw[0][2] + cntw[1][2] + cntw[2][2] + cntw[3][2];
    int c3 = cntw[0][3] + cntw[1][3] + cntw[2][3] + cntw[3][3];
    const int B0 = 0;
    const int B1 = (B0 + c0 + 3) & ~3;
    const int B2 = (B1 + c1 + 3) & ~3;
    const int B3 = (B2 + c2_ + 3) & ~3;
    const int St4 = (B3 + c3 + 3) & ~3;             // <= 268 <= SP

    if (tid < 256) {
        int offw = 0;
        #pragma unroll
        for (int w2 = 0; w2 < 4; ++w2) if (w2 < w) offw += cntw[w2][e];
        int Bsel = (e == 0) ? B0 : ((e == 1) ? B1 : ((e == 2) ? B2 : B3));
        int ci = Bsel + offw + rank;
        vca[ci] = v;
        #pragma unroll
        for (int c = 0; c < 4; ++c)
            RmT[c][ci] = x[xb + 512 + 4 * tid + c] * maskf;
    }
    __syncthreads();

    // ---- interval index per slot (pads keep kea=0, harmless) ----
    for (int a2 = tid; a2 < St4; a2 += NTHR) {
        int ev = (a2 >= B1) + (a2 >= B2) + (a2 >= B3);
        float va = vca[a2];
        const float* Ts = &Ts_l[ev * 32];
        int k = 0;
        #pragma unroll
        for (int st = 32; st >= 1; st >>= 1)
            if (k + st <= 32 && Ts[k + st - 1] <= va) k += st;
        kea[a2] = (ev * 33 + k) * 128;
    }

    // ---- T[e][c] = sum_a R_masked (boundary-bounded) ----
    {
        int te = tid >> 7, tc = (tid >> 5) & 3, tk = tid & 31;
        int s0 = (te == 0) ? B0 : ((te == 1) ? B1 : ((te == 2) ? B2 : B3));
        int s1 = (te == 0) ? B1 : ((te == 1) ? B2 : ((te == 2) ? B3 : St4));
        float ts = 0.f;
        for (int s = s0 + tk; s < s1; s += 32) ts += RmT[tc][s];
        Tpart[te][tc][tk] = ts;
    }
    __syncthreads();
    if (tid < 16) {
        float t = 0.f;
        #pragma unroll
        for (int k = 0; k < 32; ++k) t += Tpart[tid >> 2][tid & 3][k];
        T16[tid] = t;
    }   // read only after tile-loop barriers

    // ---- 5 fixed tiles of 64: 2a table h2 (batched loads), 2b select-S ----
    float S4_0 = 0.f, S4_1 = 0.f, S4_2 = 0.f, S4_3 = 0.f;
    const int i2 = tid >> 3;                 // [0,64)
    const int cc = (tid >> 1) & 3;
    const int hf = tid & 1;
    const int aw = w << 3;                   // wave's 8-a base within tile

    for (int t = 0; t < 5; ++t) {
        const int t64 = t << 6;
        // --- 2a: 8 independent AC loads per lane, fully unrolled ---
        int   ke8[8];
        float va8[8];
        #pragma unroll
        for (int u = 0; u < 8; ++u) {
            ke8[u] = kea[t64 + aw + u];
            va8[u] = vca[t64 + aw + u];
        }
        float2 ac8[8];
        #pragma unroll
        for (int u = 0; u < 8; ++u)
            ac8[u] = *(const float2*)&ACg[ke8[u] + 2 * lane];
        #pragma unroll
        for (int u = 0; u < 8; ++u)
            H2T[lane][aw + u] = fmaxf(fmaf(va8[u], ac8[u].x, ac8[u].y), 0.f);
        __syncthreads();

        // --- 2b: 8 float4 groups; branchless expert-select accumulate ---
        const float4* Hrow = (const float4*)&H2T[i2][hf * 32];
        const float4* Rrow = (const float4*)&RmT[cc][t64 + hf * 32];
        #pragma unroll 4
        for (int k = 0; k < 8; ++k) {
            float4 h4 = Hrow[k];
            float4 r4 = Rrow[k];
            float d = h4.x * r4.x;
            d = fmaf(h4.y, r4.y, d);
            d = fmaf(h4.z, r4.z, d);
            d = fmaf(h4.w, r4.w, d);
            int gs = t64 + hf * 32 + 4 * k;       // group start (4-aligned)
            int eg = (gs >= B1) + (gs >= B2) + (gs >= B3);
            S4_0 += (eg == 0) ? d : 0.f;
            S4_1 += (eg == 1) ? d : 0.f;
            S4_2 += (eg == 2) ? d : 0.f;
            S4_3 += (eg == 3) ? d : 0.f;
        }
        __syncthreads();
    }

    // ---- write S partials ----
    S2[hf][0][cc][i2] = S4_0;
    S2[hf][1][cc][i2] = S4_1;
    S2[hf][2][cc][i2] = S4_2;
    S2[hf][3][cc][i2] = S4_3;
    __syncthreads();

    // ---- P[m][c] = sum_{e,i} W3[e,i,m] S[e,i,c] + sum_e b3[e,m] T[e,c] ----
    {
        const int m  = tid & 127;
        const int cp = (tid >> 7) & 1;       // c pair {2cp, 2cp+1}
        const int ih = tid >> 8;             // expert pair {2ih, 2ih+1}
        float acc0 = 0.f, acc1 = 0.f;
        #pragma unroll
        for (int eo = 0; eo < 2; ++eo) {
            const int ee = ih * 2 + eo;
            const float* W3e = W3 + ee * 8192 + m;
            #pragma unroll 4
            for (int i4 = 0; i4 < 16; ++i4) {
                // wave-uniform addresses -> LDS broadcast reads
                float4 sA0 = *(const float4*)&S2[0][ee][2 * cp][4 * i4];
                float4 sA1 = *(const float4*)&S2[1][ee][2 * cp][4 * i4];
                float4 sB0 = *(const float4*)&S2[0][ee][2 * cp + 1][4 * i4];
                float4 sB1 = *(const float4*)&S2[1][ee][2 * cp + 1][4 * i4];
                float4 sA; sA.x = sA0.x + sA1.x; sA.y = sA0.y + sA1.y;
                           sA.z = sA0.z + sA1.z; sA.w = sA0.w + sA1.w;
                float4 sB; sB.x = sB0.x + sB1.x; sB.y = sB0.y + sB1.y;
                           sB.z = sB0.z + sB1.z; sB.w = sB0.w + sB1.w;
                const float* wp = W3e + (i4 * 4) * 128;
                float w0 = wp[0], w1 = wp[128], w2 = wp[256], w3 = wp[384];
                acc0 = fmaf(w0, sA.x, acc0); acc0 = fmaf(w1, sA.y, acc0);
                acc0 = fmaf(w2, sA.z, acc0); acc0 = fmaf(w3, sA.w, acc0);
                acc1 = fmaf(w0, sB.x, acc1); acc1 = fmaf(w1, sB.y, acc1);
                acc1 = fmaf(w2, sB.z, acc1); acc1 = fmaf(w3, sB.w, acc1);
            }
            float b3v = b3[ee * 128 + m];
            acc0 = fmaf(b3v, T16[ee * 4 + 2 * cp], acc0);
            acc1 = fmaf(b3v, T16[ee * 4 + 2 * cp + 1], acc1);
        }
        Pp[ih][m * 5 + 2 * cp]     = acc0;
        Pp[ih][m * 5 + 2 * cp + 1] = acc1;
    }
    __syncthreads();

    // ---- D[m][n] = sum_c P[m][c] P[n][c]  (Q == P[:16,:]^T) ----
    float* outb = out + (long)b * 2048;
    #pragma unroll
    for (int r = 0; r < 4; ++r) {
        int o = r * 512 + tid;
        int m = o >> 4, n = o & 15;
        float d = 0.f;
        #pragma unroll
        for (int c = 0; c < 4; ++c) {
            float pm = Pp[0][m * 5 + c] + Pp[1][m * 5 + c];
            float pn = Pp[0][n * 5 + c] + Pp[1][n * 5 + c];
            d = fmaf(pm, pn, d);
        }
        outb[o] = d;
    }
}

extern "C" void kernel_launch(void* const* d_in, const int* in_sizes, int n_in,
                              void* d_out, int out_size, void* d_ws, size_t ws_size,
                              hipStream_t stream)
{
    const float* x  = (const float*)d_in[0];
    const float* W1 = (const float*)d_in[1];
    const float* b1 = (const float*)d_in[2];
    const float* W2 = (const float*)d_in[3];
    const float* b2 = (const float*)d_in[4];
    const float* W3 = (const float*)d_in[5];
    const float* b3 = (const float*)d_in[6];
    float* out = (float*)d_out;
    float* ws  = (float*)d_ws;       // needs 68096 bytes

    be_prep<<<1, 256, 0, stream>>>(W1, b1, W2, b2, ws);
    be_kernel<<<1024, NTHR, 0, stream>>>(x, W3, b3, ws, out);
}